// Round 4
// baseline (104.312 us; speedup 1.0000x reference)
//
#include <hip/hip_runtime.h>
#include <stddef.h>

typedef unsigned short u16;
typedef unsigned int u32;
typedef __attribute__((ext_vector_type(4))) float f32x4;
typedef __attribute__((ext_vector_type(8))) u16 u16x8;
typedef __attribute__((ext_vector_type(8))) short s16x8;
typedef __attribute__((ext_vector_type(4))) u32 u32x4;

#define MFMA16 __builtin_amdgcn_mfma_f32_16x16x32_bf16

__device__ __forceinline__ float bf2f(u16 u) { return __uint_as_float(((u32)u) << 16); }
__device__ __forceinline__ u16 f2bf(float f) {
  u32 u = __float_as_uint(f);
  return (u16)((u + 0x7FFFu + ((u >> 16) & 1u)) >> 16);
}
__device__ __forceinline__ u32 cvt_pk_bf16(float lo, float hi) {
  u32 r; asm("v_cvt_pk_bf16_f32 %0, %1, %2" : "=v"(r) : "v"(lo), "v"(hi)); return r;
}

union frag_u { u32x4 u; s16x8 s; };

// B=32, T=500, C=256, H=8, d=32
// ws (32,768,000 B):
//   [0         ..16,384,000) qkbuf [16000][512] bf16 (cols 0-255=Q, 256-511=K)
//   [16,384,000..24,576,000) vt    [32][256][500] bf16 (V^T per batch)
//   [24,576,000..32,768,000) ctx   [16000][256] bf16

// ---------------------------------------------------------------------------
// Kernel 1: qkv GEMM with fused x f32->bf16 conversion in A-staging.
// [16000,768] = x[16000,256] @ W_attn[256,768] + b. BM=128 BN=64 BK=32.
__global__ __launch_bounds__(256) void gemm_qkv(
    const float* __restrict__ x, const float* __restrict__ W,
    const float* __restrict__ bias, u16* __restrict__ qkbuf, u16* __restrict__ vt)
{
  __shared__ u16 As[128][32];
  __shared__ u16 Bs[64][40];
  const int tid = threadIdx.x;
  const int lane = tid & 63;
  const int w = tid >> 6;
  const int cl = lane & 15, g = lane >> 4;
  const int m0 = blockIdx.x * 128, n0 = blockIdx.y * 64;
  const int wm = w >> 1, wn = w & 1;
  const int bn = tid & 63, bk8 = (tid >> 6) * 8;
  const int ar0 = tid >> 2, ac0 = (tid & 3) * 8;
  const int ar1 = (tid + 256) >> 2, ac1 = ((tid + 256) & 3) * 8;

  f32x4 acc[4][2];
#pragma unroll
  for (int mi = 0; mi < 4; ++mi)
#pragma unroll
    for (int ni = 0; ni < 2; ++ni) acc[mi][ni] = (f32x4){0.f, 0.f, 0.f, 0.f};

  for (int kt = 0; kt < 8; ++kt) {
    const int k0 = kt * 32;
    f32x4 a0l = *(const f32x4*)&x[(size_t)(m0 + ar0) * 256 + k0 + ac0];
    f32x4 a0h = *(const f32x4*)&x[(size_t)(m0 + ar0) * 256 + k0 + ac0 + 4];
    f32x4 a1l = *(const f32x4*)&x[(size_t)(m0 + ar1) * 256 + k0 + ac1];
    f32x4 a1h = *(const f32x4*)&x[(size_t)(m0 + ar1) * 256 + k0 + ac1 + 4];
    float wv[8];
#pragma unroll
    for (int j = 0; j < 8; ++j)
      wv[j] = W[(size_t)(k0 + bk8 + j) * 768 + n0 + bn];
    __syncthreads();
    u32x4 p0, p1;
    p0[0] = cvt_pk_bf16(a0l[0], a0l[1]); p0[1] = cvt_pk_bf16(a0l[2], a0l[3]);
    p0[2] = cvt_pk_bf16(a0h[0], a0h[1]); p0[3] = cvt_pk_bf16(a0h[2], a0h[3]);
    p1[0] = cvt_pk_bf16(a1l[0], a1l[1]); p1[1] = cvt_pk_bf16(a1l[2], a1l[3]);
    p1[2] = cvt_pk_bf16(a1h[0], a1h[1]); p1[3] = cvt_pk_bf16(a1h[2], a1h[3]);
    *(u32x4*)&As[ar0][ac0] = p0;
    *(u32x4*)&As[ar1][ac1] = p1;
    u32x4 bw;
    bw[0] = cvt_pk_bf16(wv[0], wv[1]); bw[1] = cvt_pk_bf16(wv[2], wv[3]);
    bw[2] = cvt_pk_bf16(wv[4], wv[5]); bw[3] = cvt_pk_bf16(wv[6], wv[7]);
    *(u32x4*)&Bs[bn][bk8] = bw;
    __syncthreads();
    s16x8 af[4], bfr[2];
#pragma unroll
    for (int mi = 0; mi < 4; ++mi) af[mi] = *(const s16x8*)&As[wm * 64 + mi * 16 + cl][g * 8];
#pragma unroll
    for (int ni = 0; ni < 2; ++ni) bfr[ni] = *(const s16x8*)&Bs[wn * 32 + ni * 16 + cl][g * 8];
#pragma unroll
    for (int mi = 0; mi < 4; ++mi)
#pragma unroll
      for (int ni = 0; ni < 2; ++ni)
        acc[mi][ni] = MFMA16(af[mi], bfr[ni], acc[mi][ni], 0, 0, 0);
  }
  float bb[2] = { bias[n0 + wn * 32 + cl], bias[n0 + wn * 32 + 16 + cl] };
  if (n0 < 512) {
#pragma unroll
    for (int mi = 0; mi < 4; ++mi)
#pragma unroll
      for (int ni = 0; ni < 2; ++ni)
#pragma unroll
        for (int r = 0; r < 4; ++r) {
          int m = m0 + wm * 64 + mi * 16 + g * 4 + r;
          qkbuf[(size_t)m * 512 + n0 + wn * 32 + ni * 16 + cl] = f2bf(acc[mi][ni][r] + bb[ni]);
        }
  } else {
#pragma unroll
    for (int mi = 0; mi < 4; ++mi)
#pragma unroll
      for (int ni = 0; ni < 2; ++ni) {
        int cb = n0 - 512 + wn * 32 + ni * 16 + cl;
#pragma unroll
        for (int r = 0; r < 4; ++r) {
          int m = m0 + wm * 64 + mi * 16 + g * 4 + r;
          int b2 = m / 500;
          int t2 = m - b2 * 500;
          vt[(size_t)(b2 * 256 + cb) * 500 + t2] = f2bf(acc[mi][ni][r] + bb[ni]);
        }
      }
  }
}

// ---------------------------------------------------------------------------
// Kernel 2: pred GEMM. pred[b] = sigmoid( (Q diag(pw*scale)) @ K^T ), f32 out.
// No LDS: both operands are direct 16B A/B-layout loads from qkbuf rows.
// Per 32-k chunk kt, head = kt, so pw[kt]*scale folds in as a scalar FMA.
__global__ __launch_bounds__(256) void pred_gemm(
    const u16* __restrict__ qk, const float* __restrict__ pw_g,
    float* __restrict__ pred)
{
  const int tid = threadIdx.x;
  const int lane = tid & 63;
  const int w = tid >> 6;
  const int cl = lane & 15, g = lane >> 4;
  const int lin = blockIdx.x;            // 512 = 8 xcd * 4 b * 16 tiles
  const int xcd = lin & 7, idx = lin >> 3;
  const int b = xcd * 4 + (idx >> 4);
  const int tile = idx & 15;
  const int tm = tile >> 2, tn = tile & 3;
  const int r0 = tm * 128 + (w >> 1) * 64;   // row (t) base for this wave
  const int c0 = tn * 128 + (w & 1) * 64;    // col (s) base for this wave
  const float scale = 0.17677669529663687f;

  const u16* qkb = qk + (size_t)b * 500 * 512;
  float fw[8];
#pragma unroll
  for (int h = 0; h < 8; ++h) fw[h] = pw_g[h] * scale;

  f32x4 acc[4][4];
#pragma unroll
  for (int mi = 0; mi < 4; ++mi)
#pragma unroll
    for (int ni = 0; ni < 4; ++ni) acc[mi][ni] = (f32x4){0.f, 0.f, 0.f, 0.f};

#pragma unroll 2
  for (int kt = 0; kt < 8; ++kt) {
    const int k0 = kt * 32;
    s16x8 af[4], bf[4];
#pragma unroll
    for (int mi = 0; mi < 4; ++mi) {
      int t = r0 + mi * 16 + cl; if (t > 499) t = 499;
      af[mi] = *(const s16x8*)&qkb[(size_t)t * 512 + k0 + g * 8];
    }
#pragma unroll
    for (int ni = 0; ni < 4; ++ni) {
      int s = c0 + ni * 16 + cl; if (s > 499) s = 499;
      bf[ni] = *(const s16x8*)&qkb[(size_t)s * 512 + 256 + k0 + g * 8];
    }
    const f32x4 zf = (f32x4){0.f, 0.f, 0.f, 0.f};
    const float f = fw[kt];
#pragma unroll
    for (int mi = 0; mi < 4; ++mi)
#pragma unroll
      for (int ni = 0; ni < 4; ++ni) {
        f32x4 part = MFMA16(af[mi], bf[ni], zf, 0, 0, 0);
#pragma unroll
        for (int r = 0; r < 4; ++r) acc[mi][ni][r] = fmaf(f, part[r], acc[mi][ni][r]);
      }
  }
  // sigmoid + masked store
#pragma unroll
  for (int mi = 0; mi < 4; ++mi)
#pragma unroll
    for (int ni = 0; ni < 4; ++ni) {
      const int s = c0 + ni * 16 + cl;
#pragma unroll
      for (int r = 0; r < 4; ++r) {
        const int t = r0 + mi * 16 + g * 4 + r;
        if (t < 500 && s < 500) {
          pred[(size_t)(b * 500 + t) * 500 + s] =
              1.f / (1.f + __expf(-acc[mi][ni][r]));
        }
      }
    }
}

// ---------------------------------------------------------------------------
// Kernel 3: value attention, fully wave-local (no LDS, no barriers).
// Wave = (b, h, 32 q-rows); block = 4 waves sharing (b,h) (L1/L2 reuse).
// Swapped QK^T, no-max softmax, P in regs via cvt_pk + shfl, l = f32 in-lane.
__global__ __launch_bounds__(256) void attn_value(
    const u16* __restrict__ qk, const u16* __restrict__ vt, u16* __restrict__ ctx)
{
  const int tid = threadIdx.x;
  const int w = tid >> 6;
  const int lane = tid & 63;
  const int cl = lane & 15, g = lane >> 4;
  const int lin = blockIdx.x;            // 1024 = 8 xcd * 4 b * 8 h * 4 qg
  const int xcd = lin & 7, idx = lin >> 3;
  const int b = xcd * 4 + (idx >> 5);
  const int rem = idx & 31;
  const int h = rem >> 2, qg = rem & 3;
  const int t0 = qg * 128 + w * 32;
  const float scale = 0.17677669529663687f;

  const u16* qkb = qk + (size_t)b * 500 * 512;
  const u16* vtb = vt + (size_t)b * 256 * 500;

  s16x8 qf[2];
#pragma unroll
  for (int qi = 0; qi < 2; ++qi) {
    int tq = t0 + qi * 16 + cl; if (tq > 499) tq = 499;
    qf[qi] = *(const s16x8*)&qkb[(size_t)tq * 512 + h * 32 + g * 8];
  }
  f32x4 of[2][2];
  float lsum[2] = {0.f, 0.f};
#pragma unroll
  for (int qi = 0; qi < 2; ++qi) {
    of[qi][0] = (f32x4){0.f, 0.f, 0.f, 0.f};
    of[qi][1] = (f32x4){0.f, 0.f, 0.f, 0.f};
  }
  const int sA = (g & 1) * 32 + cl;
  const int sB = sA + 16;
  const bool hiHalf = (lane >= 32);

#pragma unroll 1
  for (int st = 0; st < 8; ++st) {
    const int s0 = st * 64;
    s16x8 kf[4];
#pragma unroll
    for (int si = 0; si < 4; ++si) {
      int sr = s0 + si * 16 + cl; if (sr > 499) sr = 499;
      kf[si] = *(const s16x8*)&qkb[(size_t)sr * 512 + 256 + h * 32 + g * 8];
    }
    s16x8 vf[2][2];
#pragma unroll
    for (int di = 0; di < 2; ++di)
#pragma unroll
      for (int s32 = 0; s32 < 2; ++s32)
        vf[di][s32] = *(const s16x8*)&vtb[(size_t)(h * 32 + di * 16 + cl) * 500 +
                                          s0 + s32 * 32 + g * 8];
    const f32x4 zf = (f32x4){0.f, 0.f, 0.f, 0.f};
    u32 P2[2][4][2];
#pragma unroll
    for (int qi = 0; qi < 2; ++qi) {
#pragma unroll
      for (int si = 0; si < 4; ++si) {
        f32x4 St = MFMA16(kf[si], qf[qi], zf, 0, 0, 0);
        float pv[4];
#pragma unroll
        for (int r = 0; r < 4; ++r) {
          int sidx = s0 + si * 16 + g * 4 + r;
          float e = __expf(St[r] * scale);
          pv[r] = (sidx < 500) ? e : 0.f;
          lsum[qi] += pv[r];
        }
        P2[qi][si][0] = cvt_pk_bf16(pv[0], pv[1]);
        P2[qi][si][1] = cvt_pk_bf16(pv[2], pv[3]);
      }
    }
#pragma unroll
    for (int s32 = 0; s32 < 2; ++s32) {
#pragma unroll
      for (int qi = 0; qi < 2; ++qi) {
        u32 Z0 = hiHalf ? P2[qi][2 * s32 + 1][0] : P2[qi][2 * s32][0];
        u32 Z1 = hiHalf ? P2[qi][2 * s32 + 1][1] : P2[qi][2 * s32][1];
        frag_u fu;
        fu.u[0] = (u32)__shfl((int)Z0, sA);
        fu.u[1] = (u32)__shfl((int)Z1, sA);
        fu.u[2] = (u32)__shfl((int)Z0, sB);
        fu.u[3] = (u32)__shfl((int)Z1, sB);
        of[qi][0] = MFMA16(fu.s, vf[0][s32], of[qi][0], 0, 0, 0);
        of[qi][1] = MFMA16(fu.s, vf[1][s32], of[qi][1], 0, 0, 0);
      }
    }
  }
  // l: cross-g reduce, then redistribute to of rows via shfl
#pragma unroll
  for (int qi = 0; qi < 2; ++qi) {
    float l2 = lsum[qi] + __shfl_xor(lsum[qi], 16);
    l2 += __shfl_xor(l2, 32);
#pragma unroll
    for (int r = 0; r < 4; ++r) {
      const int tq = t0 + qi * 16 + g * 4 + r;
      if (tq < 500) {
        const float inv = 1.f / __shfl(l2, g * 4 + r);
        ctx[(size_t)(b * 500 + tq) * 256 + h * 32 + cl]      = f2bf(of[qi][0][r] * inv);
        ctx[(size_t)(b * 500 + tq) * 256 + h * 32 + 16 + cl] = f2bf(of[qi][1][r] * inv);
      }
    }
  }
}

// ---------------------------------------------------------------------------
// Kernel 4: value[16000,256](f32) = ctx[16000,256](bf16) @ W_proj + b
__global__ __launch_bounds__(256) void gemm_proj(
    const u16* __restrict__ A, const float* __restrict__ W,
    const float* __restrict__ bias, float* __restrict__ out)
{
  __shared__ u16 As[128][32];
  __shared__ u16 Bs[64][40];
  const int tid = threadIdx.x;
  const int lane = tid & 63;
  const int w = tid >> 6;
  const int cl = lane & 15, g = lane >> 4;
  const int m0 = blockIdx.x * 128, n0 = blockIdx.y * 64;
  const int wm = w >> 1, wn = w & 1;
  const int bn = tid & 63, bk8 = (tid >> 6) * 8;
  const int ar0 = tid >> 2, ac0 = (tid & 3) * 8;
  const int ar1 = (tid + 256) >> 2, ac1 = ((tid + 256) & 3) * 8;

  f32x4 acc[4][2];
#pragma unroll
  for (int mi = 0; mi < 4; ++mi)
#pragma unroll
    for (int ni = 0; ni < 2; ++ni) acc[mi][ni] = (f32x4){0.f, 0.f, 0.f, 0.f};

  for (int kt = 0; kt < 8; ++kt) {
    const int k0 = kt * 32;
    u16x8 a0 = *(const u16x8*)&A[(size_t)(m0 + ar0) * 256 + k0 + ac0];
    u16x8 a1 = *(const u16x8*)&A[(size_t)(m0 + ar1) * 256 + k0 + ac1];
    float wv[8];
#pragma unroll
    for (int j = 0; j < 8; ++j)
      wv[j] = W[(size_t)(k0 + bk8 + j) * 256 + n0 + bn];
    __syncthreads();
    *(u16x8*)&As[ar0][ac0] = a0;
    *(u16x8*)&As[ar1][ac1] = a1;
    u32x4 bw;
    bw[0] = cvt_pk_bf16(wv[0], wv[1]); bw[1] = cvt_pk_bf16(wv[2], wv[3]);
    bw[2] = cvt_pk_bf16(wv[4], wv[5]); bw[3] = cvt_pk_bf16(wv[6], wv[7]);
    *(u32x4*)&Bs[bn][bk8] = bw;
    __syncthreads();
    s16x8 af[4], bfr[2];
#pragma unroll
    for (int mi = 0; mi < 4; ++mi) af[mi] = *(const s16x8*)&As[wm * 64 + mi * 16 + cl][g * 8];
#pragma unroll
    for (int ni = 0; ni < 2; ++ni) bfr[ni] = *(const s16x8*)&Bs[wn * 32 + ni * 16 + cl][g * 8];
#pragma unroll
    for (int mi = 0; mi < 4; ++mi)
#pragma unroll
      for (int ni = 0; ni < 2; ++ni)
        acc[mi][ni] = MFMA16(af[mi], bfr[ni], acc[mi][ni], 0, 0, 0);
  }
  float bb[2] = { bias[n0 + wn * 32 + cl], bias[n0 + wn * 32 + 16 + cl] };
#pragma unroll
  for (int mi = 0; mi < 4; ++mi)
#pragma unroll
    for (int ni = 0; ni < 2; ++ni)
#pragma unroll
      for (int r = 0; r < 4; ++r) {
        int m = m0 + wm * 64 + mi * 16 + g * 4 + r;
        out[(size_t)m * 256 + n0 + wn * 32 + ni * 16 + cl] = acc[mi][ni][r] + bb[ni];
      }
}

// ---------------------------------------------------------------------------
extern "C" void kernel_launch(void* const* d_in, const int* in_sizes, int n_in,
                              void* d_out, int out_size, void* d_ws, size_t ws_size,
                              hipStream_t stream)
{
  const float* x      = (const float*)d_in[0];  // [32,500,256]
  const float* W_attn = (const float*)d_in[1];  // [256,768]
  const float* b_attn = (const float*)d_in[2];  // [768]
  const float* p_w    = (const float*)d_in[3];  // [8]
  const float* W_proj = (const float*)d_in[4];  // [256,256]
  const float* b_proj = (const float*)d_in[5];  // [256]

  float* pred   = (float*)d_out;                // [32,500,500]
  float* valout = pred + 8000000;               // [32,500,256]

  u16* qkbuf = (u16*)d_ws;                          // 16,384,000 B
  u16* vt    = (u16*)((char*)d_ws + 16384000);      //  8,192,000 B
  u16* ctx   = (u16*)((char*)d_ws + 24576000);      //  8,192,000 B

  hipLaunchKernelGGL(gemm_qkv, dim3(125, 12), dim3(256), 0, stream,
                     x, W_attn, b_attn, qkbuf, vt);
  hipLaunchKernelGGL(pred_gemm, dim3(512), dim3(256), 0, stream,
                     qkbuf, p_w, pred);
  hipLaunchKernelGGL(attn_value, dim3(1024), dim3(256), 0, stream,
                     qkbuf, vt, ctx);
  hipLaunchKernelGGL(gemm_proj, dim3(125, 4), dim3(256), 0, stream,
                     ctx, W_proj, b_proj, valout);
}